// Round 8
// baseline (263.669 us; speedup 1.0000x reference)
//
#include <hip/hip_runtime.h>

#define T_STEPS 2000
#define BATCH   2048

// Fully fused conv + recurrence, one rotating-ring wave per batch element.
//
// Ring invariant (entering step t): lane L holds
//   R_L = cba + sum_{tau<=t-1} (a[63-(t+L-tau)]/mc)*c_tau + gamma-weighted f's
// Per step t:
//   1. R += af * c_t            (af[L]=a[63-L]/mc; c_t from SGPR; lane0 -> u_t)
//   2. u = readlane(R,0); p = poly(u) (Horner)
//   3. q = med3(p, 0, 5)        (fused relu + saturation clamp)
//   4. f = M * q*(135135+17325w+378w^2+w^3)/(135135+62370w+3150w^2+28w^3),
//      w=q^2  (Pade[7/6] tanh, continued-fraction truncation; err +1.5e-5 @4,
//      +1.0e-4 @5 — 16x less than round 7's Pade[5/4], no systematic overshoot)
//   5. rotate R down one lane (DPP wave_rol:1), lane 63 <- cba (fresh slot)
//   6. R += gam * f             (gam[L]=(1000/mc)*b_lag[63-L], fixed)
//   7. F = cndmask(rotl1(F), f, lane63)   (output collector)
// One v_rcp per step is the only transcendental (exp2 eliminated).
__global__ __launch_bounds__(256) void fused_kernel(
    const float* __restrict__ currents, const float* __restrict__ a,
    const float* __restrict__ b_lag, const float* __restrict__ poly_coeff,
    const float* __restrict__ b_act, const float* __restrict__ max_current,
    const float* __restrict__ max_firing_rate, float* __restrict__ out)
{
    int tid  = threadIdx.x;
    int lane = tid & 63;
    int wid  = tid >> 6;
    int b    = blockIdx.x * 4 + wid;

    float inv = 1.0f / max_current[0];
    float cba = -b_act[0] * inv;
    float af  = a[63 - lane] * inv;                 // per-lane conv tap
    float gam = (1000.0f * inv) * b_lag[63 - lane]; // per-lane feedback tap

    // inner polynomial: p = c0^2 + c1^2 u + c2^2 u^2 + c3^2 u^3
    float c0 = poly_coeff[0], c1 = poly_coeff[1], c2 = poly_coeff[2], c3 = poly_coeff[3];
    float k0 = c0 * c0, k1 = c1 * c1, k2 = c2 * c2, k3 = c3 * c3;
    float M  = max_firing_rate[0];
    // Pade[7/6] coefficients; M folded into the numerator
    float N0 = 135135.0f * M, N1 = 17325.0f * M, N2 = 378.0f * M;  // leading w^3: M
    const float D0 = 135135.0f, D1 = 62370.0f, D2 = 3150.0f, D3 = 28.0f;

    auto rotl1 = [](float v) {   // dst[L] = src[(L+1) & 63]
        int i = __builtin_bit_cast(int, v);
        return __builtin_bit_cast(float,
            __builtin_amdgcn_update_dpp(i, i, 0x134, 0xf, 0xf, false));
    };

    // wave-uniform currents column pointer -> SGPR base, so per-chunk currents
    // become scalar loads (SMEM pipe) feeding v_fmac as SGPR operands.
    const float* ccol = currents + b;
    uint64_t pv  = (uint64_t)(uintptr_t)ccol;
    uint32_t plo = (uint32_t)__builtin_amdgcn_readfirstlane((int)(pv & 0xffffffffu));
    uint32_t phi = (uint32_t)__builtin_amdgcn_readfirstlane((int)(pv >> 32));
    const float* cc = (const float*)(uintptr_t)(((uint64_t)phi << 32) | plo);

    float* outcol = out + b;

    bool  is63 = (lane == 63);               // loop-invariant cndmask predicate
    float R = cba;                           // all slots born with the bias
    float F = 0.0f;                          // output collector

    auto step = [&](float c) {
        R = fmaf(af, c, R);                           // complete lane 0 -> u_t
        float u = __builtin_bit_cast(float,
                    __builtin_amdgcn_readlane(__builtin_bit_cast(int, R), 0));
        float p = fmaf(fmaf(fmaf(k3, u, k2), u, k1), u, k0);   // Horner
        float q = __builtin_amdgcn_fmed3f(p, 0.0f, 5.0f);      // relu + clamp
        float w = q * q;
        float N = fmaf(w, fmaf(w, fmaf(w, M,  N2), N1), N0);   // M*(135135+17325w+378w^2+w^3)
        float D = fmaf(w, fmaf(w, fmaf(w, D3, D2), D1), D0);   //    135135+62370w+3150w^2+28w^3
        float r = __builtin_amdgcn_rcpf(D);
        float f = (q * N) * r;                        // = M*tanh(q) >= 0
        float Rr = rotl1(R);                          // slots shift down one lane
        Rr = is63 ? cba : Rr;                         // fresh slot for t+64
        R  = fmaf(gam, f, Rr);
        float Fr = rotl1(F);                          // collect f in rotating reg
        F  = is63 ? f : Fr;
    };

    // 31 full chunks of 64 steps (t = 0 .. 1983)
    for (int chunk = 0; chunk < 31; ++chunk) {
        long t0 = (long)chunk * 64;
        float cs[64];                                 // wave-uniform -> s_load
#pragma unroll
        for (int s = 0; s < 64; ++s) cs[s] = cc[(t0 + s) * BATCH];
#pragma unroll
        for (int s = 0; s < 64; ++s) step(cs[s]);
        outcol[(t0 + lane) * BATCH] = F;              // lane L = f[t0+L]
    }
    // tail: 16 steps (t = 1984 .. 1999); f[1984+s] ends at lane 48+s
    {
        float cs[16];
#pragma unroll
        for (int s = 0; s < 16; ++s) cs[s] = cc[(long)(1984 + s) * BATCH];
#pragma unroll
        for (int s = 0; s < 16; ++s) step(cs[s]);
        if (lane >= 48) outcol[(long)(1984 + lane - 48) * BATCH] = F;
    }
}

extern "C" void kernel_launch(void* const* d_in, const int* in_sizes, int n_in,
                              void* d_out, int out_size, void* d_ws, size_t ws_size,
                              hipStream_t stream) {
    const float* currents   = (const float*)d_in[0];
    const float* a          = (const float*)d_in[1];
    const float* b_lag      = (const float*)d_in[2];
    const float* poly_coeff = (const float*)d_in[3];
    const float* b_act      = (const float*)d_in[4];
    const float* mc         = (const float*)d_in[5];
    const float* mfr        = (const float*)d_in[6];
    float* out = (float*)d_out;

    fused_kernel<<<BATCH / 4, 256, 0, stream>>>(
        currents, a, b_lag, poly_coeff, b_act, mc, mfr, out);
}

// Round 9
// 227.680 us; speedup vs baseline: 1.1581x; 1.1581x over previous
//
#include <hip/hip_runtime.h>

#define T_STEPS 2000
#define BATCH   2048

#define FORCE_VGPR(x) asm("" : "+v"(x))

// Static-slot ring, one wave per batch element, full 64-step chunk unroll.
//
// Lane L permanently owns targets t with t % 64 == L. Entering step t
// (s = t & 63), lane L holds the partial sum for its next target
// T_L = t + ((L - s) & 63), plus (for L == s) the completed u_t.
// Per step t:
//   1. R += tab[(L-s)&63].x * c_t   (conv tap a[63-d]/mc, d=(L-s)&63; for
//      L==s this adds a[63]*c_t, completing u_t)
//   2. u = readlane(R, s);  f = relu(M*tanh(poly(u)))  (Pade[7/6], 1 v_rcp)
//   3. lane s: R := cba  (rebirth for target t+64; cndmask)
//   4. R += tab[(L-s)&63].y * f   (feedback tap g[64-d]=1000*b_lag[64-d]/mc;
//      for the reborn lane d=0 -> g[0] — same formula, no special case)
//   5. F = (L==s) ? f : F   (output collector, shares the v_cmp with 3)
// No DPP, no exp2, no LDS in the hot loop; coefficients live in 64 float2
// VGPR pairs (compile-time indices; __launch_bounds__(256,2) -> 256 VGPR cap).
__global__ __launch_bounds__(256, 2) void fused_kernel(
    const float* __restrict__ currents, const float* __restrict__ a,
    const float* __restrict__ b_lag, const float* __restrict__ poly_coeff,
    const float* __restrict__ b_act, const float* __restrict__ max_current,
    const float* __restrict__ max_firing_rate, float* __restrict__ out)
{
    __shared__ float2 stab[64];
    int tid  = threadIdx.x;
    int lane = tid & 63;
    int wid  = tid >> 6;
    int b    = blockIdx.x * 4 + wid;

    float inv = 1.0f / max_current[0];
    if (tid < 64) {
        // stab[d].x = a[63-d]/mc ; stab[d].y = 1000*b_lag[(64-d)&63]/mc
        float2 v;
        v.x = a[63 - tid] * inv;
        v.y = (1000.0f * inv) * b_lag[(64 - tid) & 63];
        stab[tid] = v;
    }
    __syncthreads();

    // per-lane coefficient schedule: tab[s] = stab[(lane - s) & 63]
    float2 tab[64];
#pragma unroll
    for (int s = 0; s < 64; ++s) tab[s] = stab[(lane - s) & 63];

    float cba = -b_act[0] * inv;

    // inner polynomial p = k0 + k1 u + k2 u^2 + k3 u^3 (squared coeffs)
    float c0 = poly_coeff[0], c1 = poly_coeff[1], c2 = poly_coeff[2], c3 = poly_coeff[3];
    float k0 = c0 * c0, k1 = c1 * c1, k2 = c2 * c2, k3 = c3 * c3;
    float M  = max_firing_rate[0];
    // Pade[7/6] tanh, M folded into numerator; clamp q to [0,5]
    float N0 = 135135.0f * M, N1 = 17325.0f * M, N2 = 378.0f * M;
    float D0 = 135135.0f, D1 = 62370.0f, D2 = 3150.0f, D3 = 28.0f;

    // pin uniform constants in VGPRs (one-time copies, outside the loop) so
    // every poly fma has at most one SGPR operand -> no v_mov broadcasts
    FORCE_VGPR(cba);
    FORCE_VGPR(k0); FORCE_VGPR(k1); FORCE_VGPR(k2); FORCE_VGPR(k3);
    FORCE_VGPR(M);  FORCE_VGPR(N0); FORCE_VGPR(N1); FORCE_VGPR(N2);
    FORCE_VGPR(D0); FORCE_VGPR(D1); FORCE_VGPR(D2); FORCE_VGPR(D3);

    auto bcast = [](float v, int l) {
        return __builtin_bit_cast(float,
            __builtin_amdgcn_readlane(__builtin_bit_cast(int, v), l));
    };

    const float* ccol   = currents + b;
    float*       outcol = out + b;

    float R  = cba;                         // all slots born with the bias
    float F  = 0.0f;                        // output collector
    float cv = ccol[(long)lane * BATCH];    // currents c[lane] for chunk 0

    auto step = [&](int s) {
        float c = bcast(cv, s);                        // c_t (SGPR)
        R = fmaf(tab[s].x, c, R);                      // conv tap (lane s: a[63]c_t)
        float u = bcast(R, s);                         // u_t (SGPR)
        float u2 = u * u;                              // Estrin depth 2
        float a1 = fmaf(u, k1, k0);
        float a2 = fmaf(u, k3, k2);
        float p  = fmaf(u2, a2, a1);
        float q  = __builtin_amdgcn_fmed3f(p, 0.0f, 5.0f);  // relu + clamp
        float w  = q * q;
        float N  = fmaf(w, fmaf(w, fmaf(w, M,  N2), N1), N0);
        float D  = fmaf(w, fmaf(w, fmaf(w, D3, D2), D1), D0);
        float r  = __builtin_amdgcn_rcpf(D);
        float f  = (q * N) * r;                        // M*tanh(q) >= 0
        bool own = (lane == s);
        R = own ? cba : R;                             // rebirth (target t+64)
        R = fmaf(tab[s].y, f, R);                      // feedback tap (uniform)
        F = own ? f : F;                               // collect f[t0+s]
    };

    // 31 full chunks of 64 steps (t = 0 .. 1983)
    for (int chunk = 0; chunk < 31; ++chunk) {
        long t0 = (long)chunk * 64;
        long tp = t0 + 64 + lane;                      // prefetch next currents
        float cvn = (tp < T_STEPS) ? ccol[tp * BATCH] : 0.0f;
#pragma unroll
        for (int s = 0; s < 64; ++s) step(s);
        outcol[(t0 + lane) * BATCH] = F;               // lane L = f[t0+L]
        cv = cvn;
    }
    // tail: 16 steps (t = 1984 .. 1999); f collected in lanes 0..15
#pragma unroll
    for (int s = 0; s < 16; ++s) step(s);
    if (lane < 16) outcol[(long)(1984 + lane) * BATCH] = F;
}

extern "C" void kernel_launch(void* const* d_in, const int* in_sizes, int n_in,
                              void* d_out, int out_size, void* d_ws, size_t ws_size,
                              hipStream_t stream) {
    const float* currents   = (const float*)d_in[0];
    const float* a          = (const float*)d_in[1];
    const float* b_lag      = (const float*)d_in[2];
    const float* poly_coeff = (const float*)d_in[3];
    const float* b_act      = (const float*)d_in[4];
    const float* mc         = (const float*)d_in[5];
    const float* mfr        = (const float*)d_in[6];
    float* out = (float*)d_out;

    fused_kernel<<<BATCH / 4, 256, 0, stream>>>(
        currents, a, b_lag, poly_coeff, b_act, mc, mfr, out);
}